// Round 2
// baseline (2513.210 us; speedup 1.0000x reference)
//
#include <hip/hip_runtime.h>
#include <hip/hip_bf16.h>
#include <math.h>

#define B_  2
#define T_  2048
#define D_  1024
#define F_  4096
#define E_  8
#define NTOK 4096       // B_*T_
#define TOPK 2

typedef unsigned short bf16_t;

// ---- ws layout (bytes) ----
#define OFF_CNT   0                          // int[8]   (memset 0 each call)
#define OFF_BASE  32                         // int[8]
#define OFF_TIDX  64                         // int[NTOK*2]   = 32 KB (fallback)
#define OFF_TW    (64 + 32768)               // float[NTOK*2] = 32 KB (fallback)
#define OFF_LIST  (64 + 65536)               // int[8*4096]   = 128 KB
#define OFF_WGT   (64 + 65536 + 131072)      // float[8*4096] = 128 KB
#define OFF_H     (64 + 65536 + 262144)      // bf16[8192*4096] = 64 MB (16B aligned)
#define WS_NEED   (OFF_H + (size_t)8192 * 4096 * 2)

__device__ __forceinline__ float gelu_exact(float v) {
    return 0.5f * v * (1.0f + erff(v * 0.70710678118654752440f));
}

__device__ __forceinline__ unsigned short f2bf_rne(float f) {
    union { float f; unsigned int u; } v; v.f = f;
    unsigned int r = (v.u + 0x7fffu + ((v.u >> 16) & 1u)) >> 16;
    return (unsigned short)r;
}

__device__ __forceinline__ float bf2f(unsigned int u) {
    union { unsigned int i; float f; } v; v.i = u << 16; return v.f;
}

// ---------------------------------------------------------------------------
// Router: one wave per token. logits = x_row @ Wr; softmax -> top2 -> renorm.
// Writes per-token (idx,w) always; if do_lists, also builds per-expert lists.
// ---------------------------------------------------------------------------
__global__ __launch_bounds__(64) void router_kernel(
    const float* __restrict__ x, const float* __restrict__ Wr,
    int* __restrict__ top_idx, float* __restrict__ top_w,
    int* __restrict__ cnt, int* __restrict__ list, float* __restrict__ wgt,
    int do_lists)
{
    const int n = blockIdx.x;
    const int lane = threadIdx.x;
    const float* xr = x + (size_t)n * D_;

    float acc[E_];
#pragma unroll
    for (int e = 0; e < E_; ++e) acc[e] = 0.f;

    for (int d = lane; d < D_; d += 64) {
        const float xv = xr[d];
#pragma unroll
        for (int e = 0; e < E_; ++e)
            acc[e] += xv * Wr[d * E_ + e];
    }
#pragma unroll
    for (int e = 0; e < E_; ++e) {
        float v = acc[e];
#pragma unroll
        for (int off = 32; off > 0; off >>= 1)
            v += __shfl_down(v, off, 64);
        acc[e] = v;
    }
    if (lane == 0) {
        float m = acc[0];
#pragma unroll
        for (int e = 1; e < E_; ++e) m = fmaxf(m, acc[e]);
        float p[E_];
#pragma unroll
        for (int e = 0; e < E_; ++e) p[e] = __expf(acc[e] - m);
        int i0 = 0; float v0 = p[0];
#pragma unroll
        for (int e = 1; e < E_; ++e) if (p[e] > v0) { v0 = p[e]; i0 = e; }
        int i1 = (i0 == 0) ? 1 : 0; float v1 = p[i1];
#pragma unroll
        for (int e = 0; e < E_; ++e) {
            if (e == i0) continue;
            if (p[e] > v1) { v1 = p[e]; i1 = e; }
        }
        const float inv = 1.f / (v0 + v1);
        const float w0 = v0 * inv, w1 = v1 * inv;
        top_idx[n * TOPK + 0] = i0;
        top_idx[n * TOPK + 1] = i1;
        top_w[n * TOPK + 0] = w0;
        top_w[n * TOPK + 1] = w1;
        if (do_lists) {
            int p0 = atomicAdd(&cnt[i0], 1);
            list[i0 * NTOK + p0] = n;  wgt[i0 * NTOK + p0] = w0;
            int p1 = atomicAdd(&cnt[i1], 1);
            list[i1 * NTOK + p1] = n;  wgt[i1 * NTOK + p1] = w1;
        }
    }
}

__global__ void prefix_kernel(const int* __restrict__ cnt, int* __restrict__ base)
{
    if (threadIdx.x == 0 && blockIdx.x == 0) {
        int s = 0;
#pragma unroll
        for (int e = 0; e < E_; ++e) { base[e] = s; s += cnt[e]; }
    }
}

// ---------------------------------------------------------------------------
// Tiled SGEMM kernels: BM=BN=128, BK=16, 256 threads, 8x8 micro-tile.
// GEMM1: H[rows, F] = gelu(X[rows, D] @ W1[e] + b1[e])   (H stored bf16)
// GEMM2: out[n, :] += w * (H[rows, F] @ W2[e] + b2[e])   (f32 atomicAdd)
// ---------------------------------------------------------------------------
#define BM 128
#define BN 128
#define BK 16

__global__ __launch_bounds__(256) void gemm1_kernel(
    const float* __restrict__ x, const float* __restrict__ W1,
    const float* __restrict__ b1,
    const int* __restrict__ cnt, const int* __restrict__ base,
    const int* __restrict__ list, bf16_t* __restrict__ H)
{
    __shared__ __align__(16) float Xs[BK][BM + 4];   // transposed: [k][m]
    __shared__ __align__(16) float Ws[BK][BN + 4];   // [k][n]

    const int e  = blockIdx.z;
    const int ce = cnt[e];
    const int m0 = blockIdx.y * BM;
    if (m0 >= ce) return;
    const int n0 = blockIdx.x * BN;
    const int be = base[e];
    const int t  = threadIdx.x;
    const int tx = t & 15, ty = t >> 4;

    // staging roles
    const int xr_row = t >> 1;            // 0..127
    const int xr_c0  = (t & 1) * 8;       // 0 or 8
    const int p_x    = m0 + xr_row;
    const float* xrow = (p_x < ce) ? (x + (size_t)list[e * NTOK + p_x] * D_) : nullptr;
    const int wr_kk = t >> 4;             // 0..15
    const int wr_c0 = (t & 15) * 8;       // 0..120
    const float* W1e = W1 + (size_t)e * D_ * F_;

    float acc[8][8];
#pragma unroll
    for (int i = 0; i < 8; ++i)
#pragma unroll
        for (int j = 0; j < 8; ++j) acc[i][j] = 0.f;

    for (int k0 = 0; k0 < D_; k0 += BK) {
        // stage X (transposed)
        float xv[8];
        if (xrow) {
            const float4 a = *(const float4*)(xrow + k0 + xr_c0);
            const float4 b = *(const float4*)(xrow + k0 + xr_c0 + 4);
            xv[0]=a.x; xv[1]=a.y; xv[2]=a.z; xv[3]=a.w;
            xv[4]=b.x; xv[5]=b.y; xv[6]=b.z; xv[7]=b.w;
        } else {
#pragma unroll
            for (int j = 0; j < 8; ++j) xv[j] = 0.f;
        }
#pragma unroll
        for (int j = 0; j < 8; ++j) Xs[xr_c0 + j][xr_row] = xv[j];
        // stage W1
        {
            const float* wr = W1e + (size_t)(k0 + wr_kk) * F_ + (n0 + wr_c0);
            *(float4*)&Ws[wr_kk][wr_c0]     = *(const float4*)(wr);
            *(float4*)&Ws[wr_kk][wr_c0 + 4] = *(const float4*)(wr + 4);
        }
        __syncthreads();
#pragma unroll 4
        for (int kk = 0; kk < BK; ++kk) {
            float a[8], b[8];
            *(float4*)&a[0] = *(const float4*)&Xs[kk][ty * 8];
            *(float4*)&a[4] = *(const float4*)&Xs[kk][ty * 8 + 4];
            *(float4*)&b[0] = *(const float4*)&Ws[kk][tx * 8];
            *(float4*)&b[4] = *(const float4*)&Ws[kk][tx * 8 + 4];
#pragma unroll
            for (int i = 0; i < 8; ++i)
#pragma unroll
                for (int j = 0; j < 8; ++j)
                    acc[i][j] += a[i] * b[j];
        }
        __syncthreads();
    }

    // epilogue: +b1, gelu, store bf16
    const float* b1e = b1 + (size_t)e * F_;
    float bb[8];
#pragma unroll
    for (int j = 0; j < 8; ++j) bb[j] = b1e[n0 + tx * 8 + j];
#pragma unroll
    for (int i = 0; i < 8; ++i) {
        const int p = m0 + ty * 8 + i;
        if (p >= ce) continue;
        unsigned int pk[4];
#pragma unroll
        for (int jj = 0; jj < 4; ++jj) {
            const float g0 = gelu_exact(acc[i][2 * jj]     + bb[2 * jj]);
            const float g1 = gelu_exact(acc[i][2 * jj + 1] + bb[2 * jj + 1]);
            pk[jj] = (unsigned int)f2bf_rne(g0) | ((unsigned int)f2bf_rne(g1) << 16);
        }
        uint4 v; v.x = pk[0]; v.y = pk[1]; v.z = pk[2]; v.w = pk[3];
        *(uint4*)(H + (size_t)(be + p) * F_ + n0 + tx * 8) = v;
    }
}

__global__ __launch_bounds__(256) void gemm2_kernel(
    const bf16_t* __restrict__ H, const float* __restrict__ W2,
    const float* __restrict__ b2,
    const int* __restrict__ cnt, const int* __restrict__ base,
    const int* __restrict__ list, const float* __restrict__ wgt,
    float* __restrict__ out)
{
    __shared__ __align__(16) float Hs[BK][BM + 4];   // transposed: [k][m]
    __shared__ __align__(16) float Ws[BK][BN + 4];

    const int e  = blockIdx.z;
    const int ce = cnt[e];
    const int m0 = blockIdx.y * BM;
    if (m0 >= ce) return;
    const int n0 = blockIdx.x * BN;
    const int be = base[e];
    const int t  = threadIdx.x;
    const int tx = t & 15, ty = t >> 4;

    const int hr_row = t >> 1;
    const int hr_c0  = (t & 1) * 8;
    const int p_h    = m0 + hr_row;
    const bf16_t* hrow = (p_h < ce) ? (H + (size_t)(be + p_h) * F_) : nullptr;
    const int wr_kk = t >> 4;
    const int wr_c0 = (t & 15) * 8;
    const float* W2e = W2 + (size_t)e * F_ * D_;

    float acc[8][8];
#pragma unroll
    for (int i = 0; i < 8; ++i)
#pragma unroll
        for (int j = 0; j < 8; ++j) acc[i][j] = 0.f;

    for (int k0 = 0; k0 < F_; k0 += BK) {
        float hv[8];
        if (hrow) {
            const uint4 u = *(const uint4*)(hrow + k0 + hr_c0);
            hv[0] = bf2f(u.x & 0xffffu); hv[1] = bf2f(u.x >> 16);
            hv[2] = bf2f(u.y & 0xffffu); hv[3] = bf2f(u.y >> 16);
            hv[4] = bf2f(u.z & 0xffffu); hv[5] = bf2f(u.z >> 16);
            hv[6] = bf2f(u.w & 0xffffu); hv[7] = bf2f(u.w >> 16);
        } else {
#pragma unroll
            for (int j = 0; j < 8; ++j) hv[j] = 0.f;
        }
#pragma unroll
        for (int j = 0; j < 8; ++j) Hs[hr_c0 + j][hr_row] = hv[j];
        {
            const float* wr = W2e + (size_t)(k0 + wr_kk) * D_ + (n0 + wr_c0);
            *(float4*)&Ws[wr_kk][wr_c0]     = *(const float4*)(wr);
            *(float4*)&Ws[wr_kk][wr_c0 + 4] = *(const float4*)(wr + 4);
        }
        __syncthreads();
#pragma unroll 4
        for (int kk = 0; kk < BK; ++kk) {
            float a[8], b[8];
            *(float4*)&a[0] = *(const float4*)&Hs[kk][ty * 8];
            *(float4*)&a[4] = *(const float4*)&Hs[kk][ty * 8 + 4];
            *(float4*)&b[0] = *(const float4*)&Ws[kk][tx * 8];
            *(float4*)&b[4] = *(const float4*)&Ws[kk][tx * 8 + 4];
#pragma unroll
            for (int i = 0; i < 8; ++i)
#pragma unroll
                for (int j = 0; j < 8; ++j)
                    acc[i][j] += a[i] * b[j];
        }
        __syncthreads();
    }

    const float* b2e = b2 + (size_t)e * D_;
    float bb[8];
#pragma unroll
    for (int j = 0; j < 8; ++j) bb[j] = b2e[n0 + tx * 8 + j];
#pragma unroll
    for (int i = 0; i < 8; ++i) {
        const int p = m0 + ty * 8 + i;
        if (p >= ce) continue;
        const int   n = list[e * NTOK + p];
        const float w = wgt[e * NTOK + p];
        float* op = out + (size_t)n * D_ + n0 + tx * 8;
#pragma unroll
        for (int j = 0; j < 8; ++j)
            atomicAdd(&op[j], w * (acc[i][j] + bb[j]));
    }
}

// ---------------------------------------------------------------------------
// Fallback (small ws): per-token streaming kernel, f32. Slow but correct.
// ---------------------------------------------------------------------------
__global__ __launch_bounds__(256) void fallback_expert_kernel(
    const float* __restrict__ x,
    const float* __restrict__ W1, const float* __restrict__ b1,
    const float* __restrict__ W2, const float* __restrict__ b2,
    const int* __restrict__ top_idx, const float* __restrict__ top_w,
    float* __restrict__ out)
{
    __shared__ float x_lds[D_];
    __shared__ float h_lds[F_];

    const int n = blockIdx.x;
    const int t = threadIdx.x;

    ((float4*)x_lds)[t] = ((const float4*)(x + (size_t)n * D_))[t];
    __syncthreads();

    const int d0 = t * 4;
    float acc_out[4] = {0.f, 0.f, 0.f, 0.f};

    for (int k = 0; k < TOPK; ++k) {
        const int   e = top_idx[n * TOPK + k];
        const float w = top_w[n * TOPK + k];
        const float* W1e = W1 + (size_t)e * D_ * F_;
        const float* b1e = b1 + (size_t)e * F_;
#pragma unroll
        for (int tile = 0; tile < 2; ++tile) {
            const int base_f = tile * 2048 + t * 8;
            float a[8];
#pragma unroll
            for (int j = 0; j < 8; ++j) a[j] = b1e[base_f + j];
            const float4* wp = (const float4*)(W1e + base_f);
            for (int d = 0; d < D_; ++d) {
                const float4 w0 = wp[(size_t)d * (F_ / 4)];
                const float4 w1 = wp[(size_t)d * (F_ / 4) + 1];
                const float xv = x_lds[d];
                a[0] += xv * w0.x; a[1] += xv * w0.y;
                a[2] += xv * w0.z; a[3] += xv * w0.w;
                a[4] += xv * w1.x; a[5] += xv * w1.y;
                a[6] += xv * w1.z; a[7] += xv * w1.w;
            }
#pragma unroll
            for (int j = 0; j < 8; ++j)
                h_lds[base_f + j] = gelu_exact(a[j]);
        }
        __syncthreads();

        const float* W2e = W2 + (size_t)e * F_ * D_;
        const float* b2e = b2 + (size_t)e * D_;
        float y[4];
#pragma unroll
        for (int j = 0; j < 4; ++j) y[j] = b2e[d0 + j];
        const float4* wp2 = (const float4*)(W2e + d0);
        for (int f = 0; f < F_; ++f) {
            const float4 wv = wp2[(size_t)f * (D_ / 4)];
            const float hv = h_lds[f];
            y[0] += hv * wv.x; y[1] += hv * wv.y;
            y[2] += hv * wv.z; y[3] += hv * wv.w;
        }
#pragma unroll
        for (int j = 0; j < 4; ++j) acc_out[j] += w * y[j];
        __syncthreads();
    }

    float4 o; o.x = acc_out[0]; o.y = acc_out[1]; o.z = acc_out[2]; o.w = acc_out[3];
    *(float4*)(out + (size_t)n * D_ + d0) = o;
}

extern "C" void kernel_launch(void* const* d_in, const int* in_sizes, int n_in,
                              void* d_out, int out_size, void* d_ws, size_t ws_size,
                              hipStream_t stream) {
    const float* x  = (const float*)d_in[0];
    const float* Wr = (const float*)d_in[1];
    const float* W1 = (const float*)d_in[2];
    const float* b1 = (const float*)d_in[3];
    const float* W2 = (const float*)d_in[4];
    const float* b2 = (const float*)d_in[5];
    float* out = (float*)d_out;

    char* ws = (char*)d_ws;
    int*    cnt   = (int*)(ws + OFF_CNT);
    int*    basep = (int*)(ws + OFF_BASE);
    int*    tidx  = (int*)(ws + OFF_TIDX);
    float*  tw    = (float*)(ws + OFF_TW);
    int*    list  = (int*)(ws + OFF_LIST);
    float*  wgt   = (float*)(ws + OFF_WGT);
    bf16_t* H     = (bf16_t*)(ws + OFF_H);

    if (ws_size >= WS_NEED) {
        hipMemsetAsync(cnt, 0, E_ * sizeof(int), stream);
        router_kernel<<<NTOK, 64, 0, stream>>>(x, Wr, tidx, tw, cnt, list, wgt, 1);
        prefix_kernel<<<1, 64, 0, stream>>>(cnt, basep);
        hipMemsetAsync(out, 0, (size_t)NTOK * D_ * sizeof(float), stream);
        gemm1_kernel<<<dim3(F_ / BN, NTOK / BM, E_), 256, 0, stream>>>(
            x, W1, b1, cnt, basep, list, H);
        gemm2_kernel<<<dim3(D_ / BN, NTOK / BM, E_), 256, 0, stream>>>(
            H, W2, b2, cnt, basep, list, wgt, out);
    } else {
        router_kernel<<<NTOK, 64, 0, stream>>>(x, Wr, tidx, tw, cnt, list, wgt, 0);
        fallback_expert_kernel<<<NTOK, 256, 0, stream>>>(
            x, W1, b1, W2, b2, tidx, tw, out);
    }
}

// Round 3
// 728.130 us; speedup vs baseline: 3.4516x; 3.4516x over previous
//
#include <hip/hip_runtime.h>
#include <hip/hip_bf16.h>
#include <math.h>

#define B_  2
#define T_  2048
#define D_  1024
#define F_  4096
#define E_  8
#define NTOK 4096       // B_*T_
#define TOPK 2
#define NROW 8192       // NTOK*TOPK total selected rows

typedef unsigned short bf16_t;
typedef float f32x4 __attribute__((ext_vector_type(4)));
typedef int   i32x4 __attribute__((ext_vector_type(4)));

// ---- ws layout (bytes) ----
// meta (shared by all paths)
#define OFF_CNT   0                          // int[8]
#define OFF_BASE  32                         // int[8]
#define OFF_TIDX  64                         // int[NTOK*2]
#define OFF_TW    32832                      // float[NTOK*2]
#define OFF_LIST  65600                      // int[8*4096]
#define OFF_WGT   196672                     // float[8*4096]
// old (round-2) path: H at the proven offset
#define OFF_H_OLD 327744                     // bf16[8192*4096] = 64 MB
#define WS_OLD    (OFF_H_OLD + (size_t)NROW * F_ * 2)   // 67,436,608
// new (MFMA) path
#define OFF_SLOT  327744                     // int[NTOK*2]  (e<<16 | pos)
#define OFF_XB    (1u << 20)                 // bf16[NTOK*D]      8 MB
#define OFF_W1T   (OFF_XB  + (size_t)NTOK * D_ * 2)         // bf16[E*F*D] 64 MB
#define OFF_W2T   (OFF_W1T + (size_t)E_ * F_ * D_ * 2)      // bf16[E*D*F] 64 MB
#define OFF_HN    (OFF_W2T + (size_t)E_ * D_ * F_ * 2)      // bf16[NROW*F] 64 MB
#define OFF_Y     (OFF_HN  + (size_t)NROW * F_ * 2)         // f32[NROW*D] 32 MB
#define WS_MFMA   (OFF_Y   + (size_t)NROW * D_ * 4)         // ~233 MB

__device__ __forceinline__ float gelu_exact(float v) {
    return 0.5f * v * (1.0f + erff(v * 0.70710678118654752440f));
}

__device__ __forceinline__ unsigned short f2bf_rne(float f) {
    union { float f; unsigned int u; } v; v.f = f;
    unsigned int r = (v.u + 0x7fffu + ((v.u >> 16) & 1u)) >> 16;
    return (unsigned short)r;
}

__device__ __forceinline__ float bf2f(unsigned int u) {
    union { unsigned int i; float f; } v; v.i = u << 16; return v.f;
}

// async 16B/lane global->LDS; lds must be wave-uniform base (+lane*16 implicit)
__device__ __forceinline__ void gld16(const void* g, void* l) {
    __builtin_amdgcn_global_load_lds(
        (const __attribute__((address_space(1))) unsigned int*)g,
        (__attribute__((address_space(3))) unsigned int*)l, 16, 0, 0);
}

__device__ __forceinline__ void mfma16(const i32x4& a, const i32x4& b, f32x4& c) {
    asm("v_mfma_f32_16x16x32_bf16 %0, %1, %2, %0" : "+v"(c) : "v"(a), "v"(b));
}

// ---------------------------------------------------------------------------
// Router: one wave per token. mode bit0: build per-expert lists; bit1: slots.
// ---------------------------------------------------------------------------
__global__ __launch_bounds__(64) void router_kernel(
    const float* __restrict__ x, const float* __restrict__ Wr,
    int* __restrict__ top_idx, float* __restrict__ top_w,
    int* __restrict__ cnt, int* __restrict__ list, float* __restrict__ wgt,
    int* __restrict__ slot, int mode)
{
    const int n = blockIdx.x;
    const int lane = threadIdx.x;
    const float* xr = x + (size_t)n * D_;

    float acc[E_];
#pragma unroll
    for (int e = 0; e < E_; ++e) acc[e] = 0.f;

    for (int d = lane; d < D_; d += 64) {
        const float xv = xr[d];
#pragma unroll
        for (int e = 0; e < E_; ++e)
            acc[e] += xv * Wr[d * E_ + e];
    }
#pragma unroll
    for (int e = 0; e < E_; ++e) {
        float v = acc[e];
#pragma unroll
        for (int off = 32; off > 0; off >>= 1)
            v += __shfl_down(v, off, 64);
        acc[e] = v;
    }
    if (lane == 0) {
        float m = acc[0];
#pragma unroll
        for (int e = 1; e < E_; ++e) m = fmaxf(m, acc[e]);
        float p[E_];
#pragma unroll
        for (int e = 0; e < E_; ++e) p[e] = __expf(acc[e] - m);
        int i0 = 0; float v0 = p[0];
#pragma unroll
        for (int e = 1; e < E_; ++e) if (p[e] > v0) { v0 = p[e]; i0 = e; }
        int i1 = (i0 == 0) ? 1 : 0; float v1 = p[i1];
#pragma unroll
        for (int e = 0; e < E_; ++e) {
            if (e == i0) continue;
            if (p[e] > v1) { v1 = p[e]; i1 = e; }
        }
        const float inv = 1.f / (v0 + v1);
        const float w0 = v0 * inv, w1 = v1 * inv;
        top_idx[n * TOPK + 0] = i0;
        top_idx[n * TOPK + 1] = i1;
        top_w[n * TOPK + 0] = w0;
        top_w[n * TOPK + 1] = w1;
        if (mode & 1) {
            int p0 = atomicAdd(&cnt[i0], 1);
            list[i0 * NTOK + p0] = n;  wgt[i0 * NTOK + p0] = w0;
            int p1 = atomicAdd(&cnt[i1], 1);
            list[i1 * NTOK + p1] = n;  wgt[i1 * NTOK + p1] = w1;
            if (mode & 2) {
                slot[n * TOPK + 0] = (i0 << 16) | p0;
                slot[n * TOPK + 1] = (i1 << 16) | p1;
            }
        }
    }
}

__global__ void prefix_kernel(const int* __restrict__ cnt, int* __restrict__ base)
{
    if (threadIdx.x == 0 && blockIdx.x == 0) {
        int s = 0;
#pragma unroll
        for (int e = 0; e < E_; ++e) { base[e] = s; s += cnt[e]; }
    }
}

// ---------------------------------------------------------------------------
// f32 -> bf16 cast of x (4 elems/thread)
// ---------------------------------------------------------------------------
__global__ __launch_bounds__(256) void convert_x_kernel(
    const float* __restrict__ x, bf16_t* __restrict__ xb)
{
    const int i = blockIdx.x * 256 + threadIdx.x;
    const float4 v = ((const float4*)x)[i];
    uint2 o;
    o.x = (unsigned int)f2bf_rne(v.x) | ((unsigned int)f2bf_rne(v.y) << 16);
    o.y = (unsigned int)f2bf_rne(v.z) | ((unsigned int)f2bf_rne(v.w) << 16);
    ((uint2*)xb)[i] = o;
}

// ---------------------------------------------------------------------------
// Batched transpose: src f32 [Z][R][C] -> dst bf16 [Z][C][R], 64x64 tiles.
// ---------------------------------------------------------------------------
__global__ __launch_bounds__(256) void transpose_kernel(
    const float* __restrict__ src, bf16_t* __restrict__ dst, int R, int C)
{
    __shared__ float tile[64][65];
    const int z  = blockIdx.z;
    const int r0 = blockIdx.y * 64;
    const int c0 = blockIdx.x * 64;
    const float* s = src + (size_t)z * R * C;
    bf16_t*      d = dst + (size_t)z * R * C;
    const int tx = threadIdx.x & 63;
    const int ty = threadIdx.x >> 6;
#pragma unroll
    for (int i = 0; i < 16; ++i) {
        const int r = i * 4 + ty;
        tile[r][tx] = s[(size_t)(r0 + r) * C + c0 + tx];
    }
    __syncthreads();
#pragma unroll
    for (int i = 0; i < 16; ++i) {
        const int c = i * 4 + ty;
        d[(size_t)(c0 + c) * R + r0 + tx] = f2bf_rne(tile[tx][c]);
    }
}

// ---------------------------------------------------------------------------
// MFMA GEMM1: H[be+p, 0:F] = gelu(X[list[p]] @ W1T[e]^T + b1[e])
// A = Xb rows (gather), [m][k] k-contig; B = W1T[e] rows [n][k] k-contig.
// 128x128 tile, BK=32, 256 thr = 4 waves, wave = 64x64 via 4x4 16x16x32 MFMA.
// ---------------------------------------------------------------------------
__global__ __launch_bounds__(256) void mgemm1_kernel(
    const bf16_t* __restrict__ Xb, const bf16_t* __restrict__ W1T,
    const float* __restrict__ b1,
    const int* __restrict__ cnt, const int* __restrict__ base,
    const int* __restrict__ list, bf16_t* __restrict__ H)
{
    __shared__ __align__(16) bf16_t As[128 * 32];   // 8 KB [m][k]
    __shared__ __align__(16) bf16_t Bs[128 * 32];   // 8 KB [n][k]

    const int e  = blockIdx.z;
    const int ce = cnt[e];
    const int m0 = blockIdx.y * 128;
    if (m0 >= ce) return;
    const int n0 = blockIdx.x * 128;
    const int be = base[e];
    const int tid  = threadIdx.x;
    const int lane = tid & 63, wave = tid >> 6;
    const int wr = wave >> 1, wc = wave & 1;
    const int quad = lane >> 4, l16 = lane & 15;

    // staging: chunk ids tid (rows 0..63) and tid+256 (rows 64..127)
    const int mA = tid >> 2, cA = tid & 3;
    int r0i = m0 + mA;        if (r0i >= ce) r0i = ce - 1;
    int r1i = m0 + mA + 64;   if (r1i >= ce) r1i = ce - 1;
    const bf16_t* gA0 = Xb + (size_t)list[e * NTOK + r0i] * D_ + cA * 8;
    const bf16_t* gA1 = Xb + (size_t)list[e * NTOK + r1i] * D_ + cA * 8;
    const bf16_t* W1Te = W1T + (size_t)e * F_ * D_;
    const bf16_t* gB0 = W1Te + (size_t)(n0 + mA) * D_ + cA * 8;
    const bf16_t* gB1 = W1Te + (size_t)(n0 + mA + 64) * D_ + cA * 8;
    bf16_t* lA = As + wave * 512;     // wave-uniform LDS base (64 lanes * 8)
    bf16_t* lB = Bs + wave * 512;

    f32x4 acc[4][4] = {};

    for (int k0 = 0; k0 < D_; k0 += 32) {
        gld16(gA0 + k0, lA);
        gld16(gA1 + k0, lA + 2048);
        gld16(gB0 + k0, lB);
        gld16(gB1 + k0, lB + 2048);
        __syncthreads();
        i32x4 af[4], bfv[4];
#pragma unroll
        for (int i = 0; i < 4; ++i) {
            af[i]  = *(const i32x4*)(As + (wr * 64 + i * 16 + l16) * 32 + quad * 8);
            bfv[i] = *(const i32x4*)(Bs + (wc * 64 + i * 16 + l16) * 32 + quad * 8);
        }
#pragma unroll
        for (int i = 0; i < 4; ++i)
#pragma unroll
            for (int j = 0; j < 4; ++j)
                mfma16(af[i], bfv[j], acc[i][j]);
        __syncthreads();
    }
    asm volatile("s_nop 7\n\ts_nop 7");   // MFMA->VALU wait states

    const float* b1e = b1 + (size_t)e * F_;
#pragma unroll
    for (int i = 0; i < 4; ++i) {
        const int rl = wr * 64 + i * 16 + quad * 4;
#pragma unroll
        for (int j = 0; j < 4; ++j) {
            const int col = n0 + wc * 64 + j * 16 + l16;
            const float bb = b1e[col];
#pragma unroll
            for (int r = 0; r < 4; ++r) {
                const int p = m0 + rl + r;
                if (p < ce)
                    H[(size_t)(be + p) * F_ + col] = f2bf_rne(gelu_exact(acc[i][j][r] + bb));
            }
        }
    }
}

// ---------------------------------------------------------------------------
// MFMA GEMM2: Y[be+p, 0:D] = H[be+p] @ W2T[e]^T + b2[e]   (f32, unscaled)
// ---------------------------------------------------------------------------
__global__ __launch_bounds__(256) void mgemm2_kernel(
    const bf16_t* __restrict__ H, const bf16_t* __restrict__ W2T,
    const float* __restrict__ b2,
    const int* __restrict__ cnt, const int* __restrict__ base,
    float* __restrict__ Y)
{
    __shared__ __align__(16) bf16_t As[128 * 32];
    __shared__ __align__(16) bf16_t Bs[128 * 32];

    const int e  = blockIdx.z;
    const int ce = cnt[e];
    const int m0 = blockIdx.y * 128;
    if (m0 >= ce) return;
    const int n0 = blockIdx.x * 128;
    const int be = base[e];
    const int tid  = threadIdx.x;
    const int lane = tid & 63, wave = tid >> 6;
    const int wr = wave >> 1, wc = wave & 1;
    const int quad = lane >> 4, l16 = lane & 15;

    const int mA = tid >> 2, cA = tid & 3;
    int r0i = m0 + mA;        if (r0i >= ce) r0i = ce - 1;
    int r1i = m0 + mA + 64;   if (r1i >= ce) r1i = ce - 1;
    const bf16_t* gA0 = H + (size_t)(be + r0i) * F_ + cA * 8;
    const bf16_t* gA1 = H + (size_t)(be + r1i) * F_ + cA * 8;
    const bf16_t* W2Te = W2T + (size_t)e * D_ * F_;
    const bf16_t* gB0 = W2Te + (size_t)(n0 + mA) * F_ + cA * 8;
    const bf16_t* gB1 = W2Te + (size_t)(n0 + mA + 64) * F_ + cA * 8;
    bf16_t* lA = As + wave * 512;
    bf16_t* lB = Bs + wave * 512;

    f32x4 acc[4][4] = {};

    for (int k0 = 0; k0 < F_; k0 += 32) {
        gld16(gA0 + k0, lA);
        gld16(gA1 + k0, lA + 2048);
        gld16(gB0 + k0, lB);
        gld16(gB1 + k0, lB + 2048);
        __syncthreads();
        i32x4 af[4], bfv[4];
#pragma unroll
        for (int i = 0; i < 4; ++i) {
            af[i]  = *(const i32x4*)(As + (wr * 64 + i * 16 + l16) * 32 + quad * 8);
            bfv[i] = *(const i32x4*)(Bs + (wc * 64 + i * 16 + l16) * 32 + quad * 8);
        }
#pragma unroll
        for (int i = 0; i < 4; ++i)
#pragma unroll
            for (int j = 0; j < 4; ++j)
                mfma16(af[i], bfv[j], acc[i][j]);
        __syncthreads();
    }
    asm volatile("s_nop 7\n\ts_nop 7");

    const float* b2e = b2 + (size_t)e * D_;
#pragma unroll
    for (int i = 0; i < 4; ++i) {
        const int rl = wr * 64 + i * 16 + quad * 4;
#pragma unroll
        for (int j = 0; j < 4; ++j) {
            const int col = n0 + wc * 64 + j * 16 + l16;
            const float bb = b2e[col];
#pragma unroll
            for (int r = 0; r < 4; ++r) {
                const int p = m0 + rl + r;
                if (p < ce)
                    Y[(size_t)(be + p) * D_ + col] = acc[i][j][r] + bb;
            }
        }
    }
}

// ---------------------------------------------------------------------------
// Combine: out[n] = w0 * Y[row(slot0)] + w1 * Y[row(slot1)]
// ---------------------------------------------------------------------------
__global__ __launch_bounds__(256) void combine_kernel(
    const float* __restrict__ Y, const int* __restrict__ slot,
    const float* __restrict__ tw, const int* __restrict__ base,
    float* __restrict__ out)
{
    const int n = blockIdx.x;
    const int t = threadIdx.x;
    const int s0 = slot[n * TOPK + 0], s1 = slot[n * TOPK + 1];
    const float w0 = tw[n * TOPK + 0], w1 = tw[n * TOPK + 1];
    const int r0 = base[s0 >> 16] + (s0 & 0xffff);
    const int r1 = base[s1 >> 16] + (s1 & 0xffff);
    const float4 y0 = ((const float4*)(Y + (size_t)r0 * D_))[t];
    const float4 y1 = ((const float4*)(Y + (size_t)r1 * D_))[t];
    float4 o;
    o.x = w0 * y0.x + w1 * y1.x;
    o.y = w0 * y0.y + w1 * y1.y;
    o.z = w0 * y0.z + w1 * y1.z;
    o.w = w0 * y0.w + w1 * y1.w;
    ((float4*)(out + (size_t)n * D_))[t] = o;
}

// ===========================================================================
// Fallback paths (round-2 proven kernels)
// ===========================================================================
#define BM 128
#define BN 128
#define BK 16

__global__ __launch_bounds__(256) void gemm1_kernel(
    const float* __restrict__ x, const float* __restrict__ W1,
    const float* __restrict__ b1,
    const int* __restrict__ cnt, const int* __restrict__ base,
    const int* __restrict__ list, bf16_t* __restrict__ H)
{
    __shared__ __align__(16) float Xs[BK][BM + 4];
    __shared__ __align__(16) float Ws[BK][BN + 4];

    const int e  = blockIdx.z;
    const int ce = cnt[e];
    const int m0 = blockIdx.y * BM;
    if (m0 >= ce) return;
    const int n0 = blockIdx.x * BN;
    const int be = base[e];
    const int t  = threadIdx.x;
    const int tx = t & 15, ty = t >> 4;

    const int xr_row = t >> 1;
    const int xr_c0  = (t & 1) * 8;
    const int p_x    = m0 + xr_row;
    const float* xrow = (p_x < ce) ? (x + (size_t)list[e * NTOK + p_x] * D_) : nullptr;
    const int wr_kk = t >> 4;
    const int wr_c0 = (t & 15) * 8;
    const float* W1e = W1 + (size_t)e * D_ * F_;

    float acc[8][8];
#pragma unroll
    for (int i = 0; i < 8; ++i)
#pragma unroll
        for (int j = 0; j < 8; ++j) acc[i][j] = 0.f;

    for (int k0 = 0; k0 < D_; k0 += BK) {
        float xv[8];
        if (xrow) {
            const float4 a = *(const float4*)(xrow + k0 + xr_c0);
            const float4 b = *(const float4*)(xrow + k0 + xr_c0 + 4);
            xv[0]=a.x; xv[1]=a.y; xv[2]=a.z; xv[3]=a.w;
            xv[4]=b.x; xv[5]=b.y; xv[6]=b.z; xv[7]=b.w;
        } else {
#pragma unroll
            for (int j = 0; j < 8; ++j) xv[j] = 0.f;
        }
#pragma unroll
        for (int j = 0; j < 8; ++j) Xs[xr_c0 + j][xr_row] = xv[j];
        {
            const float* wr = W1e + (size_t)(k0 + wr_kk) * F_ + (n0 + wr_c0);
            *(float4*)&Ws[wr_kk][wr_c0]     = *(const float4*)(wr);
            *(float4*)&Ws[wr_kk][wr_c0 + 4] = *(const float4*)(wr + 4);
        }
        __syncthreads();
#pragma unroll 4
        for (int kk = 0; kk < BK; ++kk) {
            float a[8], b[8];
            *(float4*)&a[0] = *(const float4*)&Xs[kk][ty * 8];
            *(float4*)&a[4] = *(const float4*)&Xs[kk][ty * 8 + 4];
            *(float4*)&b[0] = *(const float4*)&Ws[kk][tx * 8];
            *(float4*)&b[4] = *(const float4*)&Ws[kk][tx * 8 + 4];
#pragma unroll
            for (int i = 0; i < 8; ++i)
#pragma unroll
                for (int j = 0; j < 8; ++j)
                    acc[i][j] += a[i] * b[j];
        }
        __syncthreads();
    }

    const float* b1e = b1 + (size_t)e * F_;
    float bb[8];
#pragma unroll
    for (int j = 0; j < 8; ++j) bb[j] = b1e[n0 + tx * 8 + j];
#pragma unroll
    for (int i = 0; i < 8; ++i) {
        const int p = m0 + ty * 8 + i;
        if (p >= ce) continue;
        unsigned int pk[4];
#pragma unroll
        for (int jj = 0; jj < 4; ++jj) {
            const float g0 = gelu_exact(acc[i][2 * jj]     + bb[2 * jj]);
            const float g1 = gelu_exact(acc[i][2 * jj + 1] + bb[2 * jj + 1]);
            pk[jj] = (unsigned int)f2bf_rne(g0) | ((unsigned int)f2bf_rne(g1) << 16);
        }
        uint4 v; v.x = pk[0]; v.y = pk[1]; v.z = pk[2]; v.w = pk[3];
        *(uint4*)(H + (size_t)(be + p) * F_ + n0 + tx * 8) = v;
    }
}

__global__ __launch_bounds__(256) void gemm2_kernel(
    const bf16_t* __restrict__ H, const float* __restrict__ W2,
    const float* __restrict__ b2,
    const int* __restrict__ cnt, const int* __restrict__ base,
    const int* __restrict__ list, const float* __restrict__ wgt,
    float* __restrict__ out)
{
    __shared__ __align__(16) float Hs[BK][BM + 4];
    __shared__ __align__(16) float Ws[BK][BN + 4];

    const int e  = blockIdx.z;
    const int ce = cnt[e];
    const int m0 = blockIdx.y * BM;
    if (m0 >= ce) return;
    const int n0 = blockIdx.x * BN;
    const int be = base[e];
    const int t  = threadIdx.x;
    const int tx = t & 15, ty = t >> 4;

    const int hr_row = t >> 1;
    const int hr_c0  = (t & 1) * 8;
    const int p_h    = m0 + hr_row;
    const bf16_t* hrow = (p_h < ce) ? (H + (size_t)(be + p_h) * F_) : nullptr;
    const int wr_kk = t >> 4;
    const int wr_c0 = (t & 15) * 8;
    const float* W2e = W2 + (size_t)e * F_ * D_;

    float acc[8][8];
#pragma unroll
    for (int i = 0; i < 8; ++i)
#pragma unroll
        for (int j = 0; j < 8; ++j) acc[i][j] = 0.f;

    for (int k0 = 0; k0 < F_; k0 += BK) {
        float hv[8];
        if (hrow) {
            const uint4 u = *(const uint4*)(hrow + k0 + hr_c0);
            hv[0] = bf2f(u.x & 0xffffu); hv[1] = bf2f(u.x >> 16);
            hv[2] = bf2f(u.y & 0xffffu); hv[3] = bf2f(u.y >> 16);
            hv[4] = bf2f(u.z & 0xffffu); hv[5] = bf2f(u.z >> 16);
            hv[6] = bf2f(u.w & 0xffffu); hv[7] = bf2f(u.w >> 16);
        } else {
#pragma unroll
            for (int j = 0; j < 8; ++j) hv[j] = 0.f;
        }
#pragma unroll
        for (int j = 0; j < 8; ++j) Hs[hr_c0 + j][hr_row] = hv[j];
        {
            const float* wr = W2e + (size_t)(k0 + wr_kk) * D_ + (n0 + wr_c0);
            *(float4*)&Ws[wr_kk][wr_c0]     = *(const float4*)(wr);
            *(float4*)&Ws[wr_kk][wr_c0 + 4] = *(const float4*)(wr + 4);
        }
        __syncthreads();
#pragma unroll 4
        for (int kk = 0; kk < BK; ++kk) {
            float a[8], b[8];
            *(float4*)&a[0] = *(const float4*)&Hs[kk][ty * 8];
            *(float4*)&a[4] = *(const float4*)&Hs[kk][ty * 8 + 4];
            *(float4*)&b[0] = *(const float4*)&Ws[kk][tx * 8];
            *(float4*)&b[4] = *(const float4*)&Ws[kk][tx * 8 + 4];
#pragma unroll
            for (int i = 0; i < 8; ++i)
#pragma unroll
                for (int j = 0; j < 8; ++j)
                    acc[i][j] += a[i] * b[j];
        }
        __syncthreads();
    }

    const float* b2e = b2 + (size_t)e * D_;
    float bb[8];
#pragma unroll
    for (int j = 0; j < 8; ++j) bb[j] = b2e[n0 + tx * 8 + j];
#pragma unroll
    for (int i = 0; i < 8; ++i) {
        const int p = m0 + ty * 8 + i;
        if (p >= ce) continue;
        const int   n = list[e * NTOK + p];
        const float w = wgt[e * NTOK + p];
        float* op = out + (size_t)n * D_ + n0 + tx * 8;
#pragma unroll
        for (int j = 0; j < 8; ++j)
            atomicAdd(&op[j], w * (acc[i][j] + bb[j]));
    }
}

__global__ __launch_bounds__(256) void fallback_expert_kernel(
    const float* __restrict__ x,
    const float* __restrict__ W1, const float* __restrict__ b1,
    const float* __restrict__ W2, const float* __restrict__ b2,
    const int* __restrict__ top_idx, const float* __restrict__ top_w,
    float* __restrict__ out)
{
    __shared__ float x_lds[D_];
    __shared__ float h_lds[F_];

    const int n = blockIdx.x;
    const int t = threadIdx.x;

    ((float4*)x_lds)[t] = ((const float4*)(x + (size_t)n * D_))[t];
    __syncthreads();

    const int d0 = t * 4;
    float acc_out[4] = {0.f, 0.f, 0.f, 0.f};

    for (int k = 0; k < TOPK; ++k) {
        const int   e = top_idx[n * TOPK + k];
        const float w = top_w[n * TOPK + k];
        const float* W1e = W1 + (size_t)e * D_ * F_;
        const float* b1e = b1 + (size_t)e * F_;
#pragma unroll
        for (int tile = 0; tile < 2; ++tile) {
            const int base_f = tile * 2048 + t * 8;
            float a[8];
#pragma unroll
            for (int j = 0; j < 8; ++j) a[j] = b1e[base_f + j];
            const float4* wp = (const float4*)(W1e + base_f);
            for (int d = 0; d < D_; ++d) {
                const float4 w0 = wp[(size_t)d * (F_ / 4)];
                const float4 w1 = wp[(size_t)d * (F_ / 4) + 1];
                const float xv = x_lds[d];
                a[0] += xv * w0.x; a[1] += xv * w0.y;
                a[2] += xv * w0.z; a[3] += xv * w0.w;
                a[4] += xv * w1.x; a[5] += xv * w1.y;
                a[6] += xv * w1.z; a[7] += xv * w1.w;
            }
#pragma unroll
            for (int j = 0; j < 8; ++j)
                h_lds[base_f + j] = gelu_exact(a[j]);
        }
        __syncthreads();

        const float* W2e = W2 + (size_t)e * F_ * D_;
        const float* b2e = b2 + (size_t)e * D_;
        float y[4];
#pragma unroll
        for (int j = 0; j < 4; ++j) y[j] = b2e[d0 + j];
        const float4* wp2 = (const float4*)(W2e + d0);
        for (int f = 0; f < F_; ++f) {
            const float4 wv = wp2[(size_t)f * (D_ / 4)];
            const float hv = h_lds[f];
            y[0] += hv * wv.x; y[1] += hv * wv.y;
            y[2] += hv * wv.z; y[3] += hv * wv.w;
        }
#pragma unroll
        for (int j = 0; j < 4; ++j) acc_out[j] += w * y[j];
        __syncthreads();
    }

    float4 o; o.x = acc_out[0]; o.y = acc_out[1]; o.z = acc_out[2]; o.w = acc_out[3];
    *(float4*)(out + (size_t)n * D_ + d0) = o;
}

extern "C" void kernel_launch(void* const* d_in, const int* in_sizes, int n_in,
                              void* d_out, int out_size, void* d_ws, size_t ws_size,
                              hipStream_t stream) {
    const float* x  = (const float*)d_in[0];
    const float* Wr = (const float*)d_in[1];
    const float* W1 = (const float*)d_in[2];
    const float* b1 = (const float*)d_in[3];
    const float* W2 = (const float*)d_in[4];
    const float* b2 = (const float*)d_in[5];
    float* out = (float*)d_out;

    char* ws = (char*)d_ws;
    int*    cnt   = (int*)(ws + OFF_CNT);
    int*    basep = (int*)(ws + OFF_BASE);
    int*    tidx  = (int*)(ws + OFF_TIDX);
    float*  tw    = (float*)(ws + OFF_TW);
    int*    list  = (int*)(ws + OFF_LIST);
    float*  wgt   = (float*)(ws + OFF_WGT);

    if (ws_size >= WS_MFMA) {
        int*    slot = (int*)(ws + OFF_SLOT);
        bf16_t* Xb   = (bf16_t*)(ws + OFF_XB);
        bf16_t* W1T  = (bf16_t*)(ws + OFF_W1T);
        bf16_t* W2T  = (bf16_t*)(ws + OFF_W2T);
        bf16_t* H    = (bf16_t*)(ws + OFF_HN);
        float*  Y    = (float*)(ws + OFF_Y);

        hipMemsetAsync(cnt, 0, E_ * sizeof(int), stream);
        router_kernel<<<NTOK, 64, 0, stream>>>(x, Wr, tidx, tw, cnt, list, wgt, slot, 3);
        prefix_kernel<<<1, 64, 0, stream>>>(cnt, basep);
        convert_x_kernel<<<NTOK * D_ / 4 / 256, 256, 0, stream>>>(x, Xb);
        transpose_kernel<<<dim3(F_ / 64, D_ / 64, E_), 256, 0, stream>>>(W1, W1T, D_, F_);
        transpose_kernel<<<dim3(D_ / 64, F_ / 64, E_), 256, 0, stream>>>(W2, W2T, F_, D_);
        mgemm1_kernel<<<dim3(F_ / 128, NTOK / 128, E_), 256, 0, stream>>>(
            Xb, W1T, b1, cnt, basep, list, H);
        mgemm2_kernel<<<dim3(D_ / 128, NTOK / 128, E_), 256, 0, stream>>>(
            H, W2T, b2, cnt, basep, Y);
        combine_kernel<<<NTOK, 256, 0, stream>>>(Y, slot, tw, basep, out);
    } else if (ws_size >= WS_OLD) {
        bf16_t* H = (bf16_t*)(ws + OFF_H_OLD);
        hipMemsetAsync(cnt, 0, E_ * sizeof(int), stream);
        router_kernel<<<NTOK, 64, 0, stream>>>(x, Wr, tidx, tw, cnt, list, wgt, nullptr, 1);
        prefix_kernel<<<1, 64, 0, stream>>>(cnt, basep);
        hipMemsetAsync(out, 0, (size_t)NTOK * D_ * sizeof(float), stream);
        gemm1_kernel<<<dim3(F_ / BN, NTOK / BM, E_), 256, 0, stream>>>(
            x, W1, b1, cnt, basep, list, H);
        gemm2_kernel<<<dim3(D_ / BN, NTOK / BM, E_), 256, 0, stream>>>(
            H, W2, b2, cnt, basep, list, wgt, out);
    } else {
        router_kernel<<<NTOK, 64, 0, stream>>>(x, Wr, tidx, tw, cnt, list, wgt, nullptr, 0);
        fallback_expert_kernel<<<NTOK, 256, 0, stream>>>(
            x, W1, b1, W2, b2, tidx, tw, out);
    }
}

// Round 4
// 711.084 us; speedup vs baseline: 3.5343x; 1.0240x over previous
//
#include <hip/hip_runtime.h>
#include <hip/hip_bf16.h>
#include <math.h>

#define B_  2
#define T_  2048
#define D_  1024
#define F_  4096
#define E_  8
#define NTOK 4096       // B_*T_
#define TOPK 2
#define NROW 8192       // NTOK*TOPK total selected rows

typedef unsigned short bf16_t;
typedef float f32x4 __attribute__((ext_vector_type(4)));
typedef int   i32x4 __attribute__((ext_vector_type(4)));

// ---- ws layout (bytes) ----
#define OFF_CNT   0                          // int[8]
#define OFF_BASE  32                         // int[8]
#define OFF_TIDX  64                         // int[NTOK*2]
#define OFF_TW    32832                      // float[NTOK*2]
#define OFF_LIST  65600                      // int[8*4096]
#define OFF_WGT   196672                     // float[8*4096]
// old (round-2) path
#define OFF_H_OLD 327744                     // bf16[8192*4096] = 64 MB
#define WS_OLD    (OFF_H_OLD + (size_t)NROW * F_ * 2)
// MFMA path
#define OFF_SLOT  327744                     // int[NTOK*2]  (e<<16 | pos)
#define OFF_XB    (1u << 20)                 // bf16[NTOK*D]      8 MB
#define OFF_W1T   (OFF_XB  + (size_t)NTOK * D_ * 2)         // bf16[E*F*D] 64 MB
#define OFF_W2T   (OFF_W1T + (size_t)E_ * F_ * D_ * 2)      // bf16[E*D*F] 64 MB
#define OFF_HN    (OFF_W2T + (size_t)E_ * D_ * F_ * 2)      // bf16[NROW*F] 64 MB
#define OFF_Y     (OFF_HN  + (size_t)NROW * F_ * 2)         // f32[NROW*D] per slab
#define WS_MFMA   (OFF_Y + (size_t)NROW * D_ * 4)           // 1 slab  (~233 MB)
#define WS_MFMA2  (OFF_Y + 2 * (size_t)NROW * D_ * 4)       // 2 slabs (~265 MB)

__device__ __forceinline__ float gelu_exact(float v) {
    return 0.5f * v * (1.0f + erff(v * 0.70710678118654752440f));
}

__device__ __forceinline__ unsigned short f2bf_rne(float f) {
    union { float f; unsigned int u; } v; v.f = f;
    unsigned int r = (v.u + 0x7fffu + ((v.u >> 16) & 1u)) >> 16;
    return (unsigned short)r;
}

__device__ __forceinline__ float bf2f(unsigned int u) {
    union { unsigned int i; float f; } v; v.i = u << 16; return v.f;
}

// async 16B/lane global->LDS; lds base wave-uniform (+lane*16 implicit)
__device__ __forceinline__ void gld16(const void* g, void* l) {
    __builtin_amdgcn_global_load_lds(
        (const __attribute__((address_space(1))) unsigned int*)g,
        (__attribute__((address_space(3))) unsigned int*)l, 16, 0, 0);
}

__device__ __forceinline__ void mfma16(const i32x4& a, const i32x4& b, f32x4& c) {
    asm("v_mfma_f32_16x16x32_bf16 %0, %1, %2, %0" : "+v"(c) : "v"(a), "v"(b));
}

// ---------------------------------------------------------------------------
// Router
// ---------------------------------------------------------------------------
__global__ __launch_bounds__(64) void router_kernel(
    const float* __restrict__ x, const float* __restrict__ Wr,
    int* __restrict__ top_idx, float* __restrict__ top_w,
    int* __restrict__ cnt, int* __restrict__ list, float* __restrict__ wgt,
    int* __restrict__ slot, int mode)
{
    const int n = blockIdx.x;
    const int lane = threadIdx.x;
    const float* xr = x + (size_t)n * D_;

    float acc[E_];
#pragma unroll
    for (int e = 0; e < E_; ++e) acc[e] = 0.f;

    for (int d = lane; d < D_; d += 64) {
        const float xv = xr[d];
#pragma unroll
        for (int e = 0; e < E_; ++e)
            acc[e] += xv * Wr[d * E_ + e];
    }
#pragma unroll
    for (int e = 0; e < E_; ++e) {
        float v = acc[e];
#pragma unroll
        for (int off = 32; off > 0; off >>= 1)
            v += __shfl_down(v, off, 64);
        acc[e] = v;
    }
    if (lane == 0) {
        float m = acc[0];
#pragma unroll
        for (int e = 1; e < E_; ++e) m = fmaxf(m, acc[e]);
        float p[E_];
#pragma unroll
        for (int e = 0; e < E_; ++e) p[e] = __expf(acc[e] - m);
        int i0 = 0; float v0 = p[0];
#pragma unroll
        for (int e = 1; e < E_; ++e) if (p[e] > v0) { v0 = p[e]; i0 = e; }
        int i1 = (i0 == 0) ? 1 : 0; float v1 = p[i1];
#pragma unroll
        for (int e = 0; e < E_; ++e) {
            if (e == i0) continue;
            if (p[e] > v1) { v1 = p[e]; i1 = e; }
        }
        const float inv = 1.f / (v0 + v1);
        const float w0 = v0 * inv, w1 = v1 * inv;
        top_idx[n * TOPK + 0] = i0;
        top_idx[n * TOPK + 1] = i1;
        top_w[n * TOPK + 0] = w0;
        top_w[n * TOPK + 1] = w1;
        if (mode & 1) {
            int p0 = atomicAdd(&cnt[i0], 1);
            list[i0 * NTOK + p0] = n;  wgt[i0 * NTOK + p0] = w0;
            int p1 = atomicAdd(&cnt[i1], 1);
            list[i1 * NTOK + p1] = n;  wgt[i1 * NTOK + p1] = w1;
            if (mode & 2) {
                slot[n * TOPK + 0] = (i0 << 16) | p0;
                slot[n * TOPK + 1] = (i1 << 16) | p1;
            }
        }
    }
}

__global__ void prefix_kernel(const int* __restrict__ cnt, int* __restrict__ base)
{
    if (threadIdx.x == 0 && blockIdx.x == 0) {
        int s = 0;
#pragma unroll
        for (int e = 0; e < E_; ++e) { base[e] = s; s += cnt[e]; }
    }
}

// ---------------------------------------------------------------------------
// f32 -> bf16 cast of x
// ---------------------------------------------------------------------------
__global__ __launch_bounds__(256) void convert_x_kernel(
    const float* __restrict__ x, bf16_t* __restrict__ xb)
{
    const int i = blockIdx.x * 256 + threadIdx.x;
    const float4 v = ((const float4*)x)[i];
    uint2 o;
    o.x = (unsigned int)f2bf_rne(v.x) | ((unsigned int)f2bf_rne(v.y) << 16);
    o.y = (unsigned int)f2bf_rne(v.z) | ((unsigned int)f2bf_rne(v.w) << 16);
    ((uint2*)xb)[i] = o;
}

// ---------------------------------------------------------------------------
// Batched transpose: src f32 [Z][R][C] -> dst bf16 [Z][C][R], 64x64 tiles.
// Write phase packs 4 bf16 (8 B) per lane, conflict-free LDS reads.
// ---------------------------------------------------------------------------
__global__ __launch_bounds__(256) void transpose_kernel(
    const float* __restrict__ src, bf16_t* __restrict__ dst, int R, int C)
{
    __shared__ float tile[64][65];
    const int z  = blockIdx.z;
    const int r0 = blockIdx.y * 64;
    const int c0 = blockIdx.x * 64;
    const float* s = src + (size_t)z * R * C;
    bf16_t*      d = dst + (size_t)z * R * C;
    const int tx = threadIdx.x & 63;
    const int ty = threadIdx.x >> 6;
#pragma unroll
    for (int i = 0; i < 16; ++i) {
        const int r = i * 4 + ty;
        tile[r][tx] = s[(size_t)(r0 + r) * C + c0 + tx];
    }
    __syncthreads();
    const int rc = (threadIdx.x & 15) * 4;
    const int cc = threadIdx.x >> 4;   // 0..15
#pragma unroll
    for (int i = 0; i < 4; ++i) {
        const int c = i * 16 + cc;
        uint2 o;
        o.x = (unsigned int)f2bf_rne(tile[rc    ][c]) | ((unsigned int)f2bf_rne(tile[rc + 1][c]) << 16);
        o.y = (unsigned int)f2bf_rne(tile[rc + 2][c]) | ((unsigned int)f2bf_rne(tile[rc + 3][c]) << 16);
        *(uint2*)(d + (size_t)(c0 + c) * R + r0 + rc) = o;
    }
}

// ---------------------------------------------------------------------------
// MFMA GEMM1 (double-buffered): H[be+p] = gelu(X[list[p]] @ W1T[e]^T + b1[e])
// 128x128 tile, BK=32, 4 waves, wave=64x64 via 4x4 16x16x32 MFMA.
// ---------------------------------------------------------------------------
__global__ __launch_bounds__(256) void mgemm1_kernel(
    const bf16_t* __restrict__ Xb, const bf16_t* __restrict__ W1T,
    const float* __restrict__ b1,
    const int* __restrict__ cnt, const int* __restrict__ base,
    const int* __restrict__ list, bf16_t* __restrict__ H)
{
    __shared__ __align__(16) bf16_t As[2][128 * 32];   // 2 x 8 KB
    __shared__ __align__(16) bf16_t Bs[2][128 * 32];

    const int e  = blockIdx.z;
    const int ce = cnt[e];
    const int m0 = blockIdx.y * 128;
    if (m0 >= ce) return;
    const int n0 = blockIdx.x * 128;
    const int be = base[e];
    const int tid  = threadIdx.x;
    const int lane = tid & 63, wave = tid >> 6;
    const int wr = wave >> 1, wc = wave & 1;
    const int quad = lane >> 4, l16 = lane & 15;

    const int mA = tid >> 2, cA = tid & 3;
    int r0i = m0 + mA;        if (r0i >= ce) r0i = ce - 1;
    int r1i = m0 + mA + 64;   if (r1i >= ce) r1i = ce - 1;
    const bf16_t* gA0 = Xb + (size_t)list[e * NTOK + r0i] * D_ + cA * 8;
    const bf16_t* gA1 = Xb + (size_t)list[e * NTOK + r1i] * D_ + cA * 8;
    const bf16_t* W1Te = W1T + (size_t)e * F_ * D_;
    const bf16_t* gB0 = W1Te + (size_t)(n0 + mA) * D_ + cA * 8;
    const bf16_t* gB1 = W1Te + (size_t)(n0 + mA + 64) * D_ + cA * 8;

    f32x4 acc[4][4] = {};

#define PREF1(bufi, kk) do { \
        gld16(gA0 + (kk), As[bufi] + wave * 512); \
        gld16(gA1 + (kk), As[bufi] + 2048 + wave * 512); \
        gld16(gB0 + (kk), Bs[bufi] + wave * 512); \
        gld16(gB1 + (kk), Bs[bufi] + 2048 + wave * 512); } while (0)

    PREF1(0, 0);
    int buf = 0;
    for (int k0 = 0; k0 < D_; k0 += 32) {
        __syncthreads();                       // drains vmcnt for buf
        if (k0 + 32 < D_) PREF1(buf ^ 1, k0 + 32);   // overlap with compute
        i32x4 af[4], bfv[4];
#pragma unroll
        for (int i = 0; i < 4; ++i) {
            af[i]  = *(const i32x4*)(As[buf] + (wr * 64 + i * 16 + l16) * 32 + quad * 8);
            bfv[i] = *(const i32x4*)(Bs[buf] + (wc * 64 + i * 16 + l16) * 32 + quad * 8);
        }
#pragma unroll
        for (int i = 0; i < 4; ++i)
#pragma unroll
            for (int j = 0; j < 4; ++j)
                mfma16(af[i], bfv[j], acc[i][j]);
        buf ^= 1;
    }
#undef PREF1
    asm volatile("s_nop 7\n\ts_nop 7");

    const float* b1e = b1 + (size_t)e * F_;
#pragma unroll
    for (int i = 0; i < 4; ++i) {
        const int rl = wr * 64 + i * 16 + quad * 4;
#pragma unroll
        for (int j = 0; j < 4; ++j) {
            const int col = n0 + wc * 64 + j * 16 + l16;
            const float bb = b1e[col];
#pragma unroll
            for (int r = 0; r < 4; ++r) {
                const int p = m0 + rl + r;
                if (p < ce)
                    H[(size_t)(be + p) * F_ + col] = f2bf_rne(gelu_exact(acc[i][j][r] + bb));
            }
        }
    }
}

// ---------------------------------------------------------------------------
// MFMA GEMM2 (double-buffered, split-K): Y_s[be+p] = H[be+p] @ W2T[e]^T (+b2)
// grid.z = E * kslabs; slab s covers k in [s*F/kslabs, ...). Bias in slab 0.
// ---------------------------------------------------------------------------
__global__ __launch_bounds__(256) void mgemm2_kernel(
    const bf16_t* __restrict__ H, const bf16_t* __restrict__ W2T,
    const float* __restrict__ b2,
    const int* __restrict__ cnt, const int* __restrict__ base,
    float* __restrict__ Y)
{
    __shared__ __align__(16) bf16_t As[2][128 * 32];
    __shared__ __align__(16) bf16_t Bs[2][128 * 32];

    const int kslabs = gridDim.z / E_;
    const int e  = blockIdx.z % E_;
    const int s  = blockIdx.z / E_;
    const int ce = cnt[e];
    const int m0 = blockIdx.y * 128;
    if (m0 >= ce) return;
    const int klen  = F_ / kslabs;
    const int kbase = s * klen;
    const int n0 = blockIdx.x * 128;
    const int be = base[e];
    const int tid  = threadIdx.x;
    const int lane = tid & 63, wave = tid >> 6;
    const int wr = wave >> 1, wc = wave & 1;
    const int quad = lane >> 4, l16 = lane & 15;

    const int mA = tid >> 2, cA = tid & 3;
    int r0i = m0 + mA;        if (r0i >= ce) r0i = ce - 1;
    int r1i = m0 + mA + 64;   if (r1i >= ce) r1i = ce - 1;
    const bf16_t* gA0 = H + (size_t)(be + r0i) * F_ + cA * 8 + kbase;
    const bf16_t* gA1 = H + (size_t)(be + r1i) * F_ + cA * 8 + kbase;
    const bf16_t* W2Te = W2T + (size_t)e * D_ * F_;
    const bf16_t* gB0 = W2Te + (size_t)(n0 + mA) * F_ + cA * 8 + kbase;
    const bf16_t* gB1 = W2Te + (size_t)(n0 + mA + 64) * F_ + cA * 8 + kbase;

    f32x4 acc[4][4] = {};

#define PREF2(bufi, kk) do { \
        gld16(gA0 + (kk), As[bufi] + wave * 512); \
        gld16(gA1 + (kk), As[bufi] + 2048 + wave * 512); \
        gld16(gB0 + (kk), Bs[bufi] + wave * 512); \
        gld16(gB1 + (kk), Bs[bufi] + 2048 + wave * 512); } while (0)

    PREF2(0, 0);
    int buf = 0;
    for (int k0 = 0; k0 < klen; k0 += 32) {
        __syncthreads();
        if (k0 + 32 < klen) PREF2(buf ^ 1, k0 + 32);
        i32x4 af[4], bfv[4];
#pragma unroll
        for (int i = 0; i < 4; ++i) {
            af[i]  = *(const i32x4*)(As[buf] + (wr * 64 + i * 16 + l16) * 32 + quad * 8);
            bfv[i] = *(const i32x4*)(Bs[buf] + (wc * 64 + i * 16 + l16) * 32 + quad * 8);
        }
#pragma unroll
        for (int i = 0; i < 4; ++i)
#pragma unroll
            for (int j = 0; j < 4; ++j)
                mfma16(af[i], bfv[j], acc[i][j]);
        buf ^= 1;
    }
#undef PREF2
    asm volatile("s_nop 7\n\ts_nop 7");

    float* Ys = Y + (size_t)s * NROW * D_;
    const float* b2e = b2 + (size_t)e * D_;
#pragma unroll
    for (int i = 0; i < 4; ++i) {
        const int rl = wr * 64 + i * 16 + quad * 4;
#pragma unroll
        for (int j = 0; j < 4; ++j) {
            const int col = n0 + wc * 64 + j * 16 + l16;
            const float bb = (s == 0) ? b2e[col] : 0.f;
#pragma unroll
            for (int r = 0; r < 4; ++r) {
                const int p = m0 + rl + r;
                if (p < ce)
                    Ys[(size_t)(be + p) * D_ + col] = acc[i][j][r] + bb;
            }
        }
    }
}

// ---------------------------------------------------------------------------
// Combine: out[n] = sum_k w_k * (sum_s Y_s[row_k])
// ---------------------------------------------------------------------------
__global__ __launch_bounds__(256) void combine_kernel(
    const float* __restrict__ Y, const int* __restrict__ slot,
    const float* __restrict__ tw, const int* __restrict__ base,
    float* __restrict__ out, int kslabs)
{
    const int n = blockIdx.x;
    const int t = threadIdx.x;
    const int s0 = slot[n * TOPK + 0], s1 = slot[n * TOPK + 1];
    const float w0 = tw[n * TOPK + 0], w1 = tw[n * TOPK + 1];
    const int r0 = base[s0 >> 16] + (s0 & 0xffff);
    const int r1 = base[s1 >> 16] + (s1 & 0xffff);
    float4 y0 = ((const float4*)(Y + (size_t)r0 * D_))[t];
    float4 y1 = ((const float4*)(Y + (size_t)r1 * D_))[t];
    if (kslabs == 2) {
        const float* Y1 = Y + (size_t)NROW * D_;
        const float4 a = ((const float4*)(Y1 + (size_t)r0 * D_))[t];
        const float4 b = ((const float4*)(Y1 + (size_t)r1 * D_))[t];
        y0.x += a.x; y0.y += a.y; y0.z += a.z; y0.w += a.w;
        y1.x += b.x; y1.y += b.y; y1.z += b.z; y1.w += b.w;
    }
    float4 o;
    o.x = w0 * y0.x + w1 * y1.x;
    o.y = w0 * y0.y + w1 * y1.y;
    o.z = w0 * y0.z + w1 * y1.z;
    o.w = w0 * y0.w + w1 * y1.w;
    ((float4*)(out + (size_t)n * D_))[t] = o;
}

// ===========================================================================
// Fallback paths (round-2 proven kernels)
// ===========================================================================
#define BM 128
#define BN 128
#define BK 16

__global__ __launch_bounds__(256) void gemm1_kernel(
    const float* __restrict__ x, const float* __restrict__ W1,
    const float* __restrict__ b1,
    const int* __restrict__ cnt, const int* __restrict__ base,
    const int* __restrict__ list, bf16_t* __restrict__ H)
{
    __shared__ __align__(16) float Xs[BK][BM + 4];
    __shared__ __align__(16) float Ws[BK][BN + 4];

    const int e  = blockIdx.z;
    const int ce = cnt[e];
    const int m0 = blockIdx.y * BM;
    if (m0 >= ce) return;
    const int n0 = blockIdx.x * BN;
    const int be = base[e];
    const int t  = threadIdx.x;
    const int tx = t & 15, ty = t >> 4;

    const int xr_row = t >> 1;
    const int xr_c0  = (t & 1) * 8;
    const int p_x    = m0 + xr_row;
    const float* xrow = (p_x < ce) ? (x + (size_t)list[e * NTOK + p_x] * D_) : nullptr;
    const int wr_kk = t >> 4;
    const int wr_c0 = (t & 15) * 8;
    const float* W1e = W1 + (size_t)e * D_ * F_;

    float acc[8][8];
#pragma unroll
    for (int i = 0; i < 8; ++i)
#pragma unroll
        for (int j = 0; j < 8; ++j) acc[i][j] = 0.f;

    for (int k0 = 0; k0 < D_; k0 += BK) {
        float xv[8];
        if (xrow) {
            const float4 a = *(const float4*)(xrow + k0 + xr_c0);
            const float4 b = *(const float4*)(xrow + k0 + xr_c0 + 4);
            xv[0]=a.x; xv[1]=a.y; xv[2]=a.z; xv[3]=a.w;
            xv[4]=b.x; xv[5]=b.y; xv[6]=b.z; xv[7]=b.w;
        } else {
#pragma unroll
            for (int j = 0; j < 8; ++j) xv[j] = 0.f;
        }
#pragma unroll
        for (int j = 0; j < 8; ++j) Xs[xr_c0 + j][xr_row] = xv[j];
        {
            const float* wr = W1e + (size_t)(k0 + wr_kk) * F_ + (n0 + wr_c0);
            *(float4*)&Ws[wr_kk][wr_c0]     = *(const float4*)(wr);
            *(float4*)&Ws[wr_kk][wr_c0 + 4] = *(const float4*)(wr + 4);
        }
        __syncthreads();
#pragma unroll 4
        for (int kk = 0; kk < BK; ++kk) {
            float a[8], b[8];
            *(float4*)&a[0] = *(const float4*)&Xs[kk][ty * 8];
            *(float4*)&a[4] = *(const float4*)&Xs[kk][ty * 8 + 4];
            *(float4*)&b[0] = *(const float4*)&Ws[kk][tx * 8];
            *(float4*)&b[4] = *(const float4*)&Ws[kk][tx * 8 + 4];
#pragma unroll
            for (int i = 0; i < 8; ++i)
#pragma unroll
                for (int j = 0; j < 8; ++j)
                    acc[i][j] += a[i] * b[j];
        }
        __syncthreads();
    }

    const float* b1e = b1 + (size_t)e * F_;
    float bb[8];
#pragma unroll
    for (int j = 0; j < 8; ++j) bb[j] = b1e[n0 + tx * 8 + j];
#pragma unroll
    for (int i = 0; i < 8; ++i) {
        const int p = m0 + ty * 8 + i;
        if (p >= ce) continue;
        unsigned int pk[4];
#pragma unroll
        for (int jj = 0; jj < 4; ++jj) {
            const float g0 = gelu_exact(acc[i][2 * jj]     + bb[2 * jj]);
            const float g1 = gelu_exact(acc[i][2 * jj + 1] + bb[2 * jj + 1]);
            pk[jj] = (unsigned int)f2bf_rne(g0) | ((unsigned int)f2bf_rne(g1) << 16);
        }
        uint4 v; v.x = pk[0]; v.y = pk[1]; v.z = pk[2]; v.w = pk[3];
        *(uint4*)(H + (size_t)(be + p) * F_ + n0 + tx * 8) = v;
    }
}

__global__ __launch_bounds__(256) void gemm2_kernel(
    const bf16_t* __restrict__ H, const float* __restrict__ W2,
    const float* __restrict__ b2,
    const int* __restrict__ cnt, const int* __restrict__ base,
    const int* __restrict__ list, const float* __restrict__ wgt,
    float* __restrict__ out)
{
    __shared__ __align__(16) float Hs[BK][BM + 4];
    __shared__ __align__(16) float Ws[BK][BN + 4];

    const int e  = blockIdx.z;
    const int ce = cnt[e];
    const int m0 = blockIdx.y * BM;
    if (m0 >= ce) return;
    const int n0 = blockIdx.x * BN;
    const int be = base[e];
    const int t  = threadIdx.x;
    const int tx = t & 15, ty = t >> 4;

    const int hr_row = t >> 1;
    const int hr_c0  = (t & 1) * 8;
    const int p_h    = m0 + hr_row;
    const bf16_t* hrow = (p_h < ce) ? (H + (size_t)(be + p_h) * F_) : nullptr;
    const int wr_kk = t >> 4;
    const int wr_c0 = (t & 15) * 8;
    const float* W2e = W2 + (size_t)e * F_ * D_;

    float acc[8][8];
#pragma unroll
    for (int i = 0; i < 8; ++i)
#pragma unroll
        for (int j = 0; j < 8; ++j) acc[i][j] = 0.f;

    for (int k0 = 0; k0 < F_; k0 += BK) {
        float hv[8];
        if (hrow) {
            const uint4 u = *(const uint4*)(hrow + k0 + hr_c0);
            hv[0] = bf2f(u.x & 0xffffu); hv[1] = bf2f(u.x >> 16);
            hv[2] = bf2f(u.y & 0xffffu); hv[3] = bf2f(u.y >> 16);
            hv[4] = bf2f(u.z & 0xffffu); hv[5] = bf2f(u.z >> 16);
            hv[6] = bf2f(u.w & 0xffffu); hv[7] = bf2f(u.w >> 16);
        } else {
#pragma unroll
            for (int j = 0; j < 8; ++j) hv[j] = 0.f;
        }
#pragma unroll
        for (int j = 0; j < 8; ++j) Hs[hr_c0 + j][hr_row] = hv[j];
        {
            const float* wr = W2e + (size_t)(k0 + wr_kk) * D_ + (n0 + wr_c0);
            *(float4*)&Ws[wr_kk][wr_c0]     = *(const float4*)(wr);
            *(float4*)&Ws[wr_kk][wr_c0 + 4] = *(const float4*)(wr + 4);
        }
        __syncthreads();
#pragma unroll 4
        for (int kk = 0; kk < BK; ++kk) {
            float a[8], b[8];
            *(float4*)&a[0] = *(const float4*)&Hs[kk][ty * 8];
            *(float4*)&a[4] = *(const float4*)&Hs[kk][ty * 8 + 4];
            *(float4*)&b[0] = *(const float4*)&Ws[kk][tx * 8];
            *(float4*)&b[4] = *(const float4*)&Ws[kk][tx * 8 + 4];
#pragma unroll
            for (int i = 0; i < 8; ++i)
#pragma unroll
                for (int j = 0; j < 8; ++j)
                    acc[i][j] += a[i] * b[j];
        }
        __syncthreads();
    }

    const float* b2e = b2 + (size_t)e * D_;
    float bb[8];
#pragma unroll
    for (int j = 0; j < 8; ++j) bb[j] = b2e[n0 + tx * 8 + j];
#pragma unroll
    for (int i = 0; i < 8; ++i) {
        const int p = m0 + ty * 8 + i;
        if (p >= ce) continue;
        const int   n = list[e * NTOK + p];
        const float w = wgt[e * NTOK + p];
        float* op = out + (size_t)n * D_ + n0 + tx * 8;
#pragma unroll
        for (int j = 0; j < 8; ++j)
            atomicAdd(&op[j], w * (acc[i][j] + bb[j]));
    }
}

__global__ __launch_bounds__(256) void fallback_expert_kernel(
    const float* __restrict__ x,
    const float* __restrict__ W1, const float* __restrict__ b1,
    const float* __restrict__ W2, const float* __restrict__ b2,
    const int* __restrict__ top_idx, const float* __restrict__ top_w,
    float* __restrict__ out)
{
    __shared__ float x_lds[D_];
    __shared__ float h_lds[F_];

    const int n = blockIdx.x;
    const int t = threadIdx.x;

    ((float4*)x_lds)[t] = ((const float4*)(x + (size_t)n * D_))[t];
    __syncthreads();

    const int d0 = t * 4;
    float acc_out[4] = {0.f, 0.f, 0.f, 0.f};

    for (int k = 0; k < TOPK; ++k) {
        const int   e = top_idx[n * TOPK + k];
        const float w = top_w[n * TOPK + k];
        const float* W1e = W1 + (size_t)e * D_ * F_;
        const float* b1e = b1 + (size_t)e * F_;
#pragma unroll
        for (int tile = 0; tile < 2; ++tile) {
            const int base_f = tile * 2048 + t * 8;
            float a[8];
#pragma unroll
            for (int j = 0; j < 8; ++j) a[j] = b1e[base_f + j];
            const float4* wp = (const float4*)(W1e + base_f);
            for (int d = 0; d < D_; ++d) {
                const float4 w0 = wp[(size_t)d * (F_ / 4)];
                const float4 w1 = wp[(size_t)d * (F_ / 4) + 1];
                const float xv = x_lds[d];
                a[0] += xv * w0.x; a[1] += xv * w0.y;
                a[2] += xv * w0.z; a[3] += xv * w0.w;
                a[4] += xv * w1.x; a[5] += xv * w1.y;
                a[6] += xv * w1.z; a[7] += xv * w1.w;
            }
#pragma unroll
            for (int j = 0; j < 8; ++j)
                h_lds[base_f + j] = gelu_exact(a[j]);
        }
        __syncthreads();

        const float* W2e = W2 + (size_t)e * F_ * D_;
        const float* b2e = b2 + (size_t)e * D_;
        float y[4];
#pragma unroll
        for (int j = 0; j < 4; ++j) y[j] = b2e[d0 + j];
        const float4* wp2 = (const float4*)(W2e + d0);
        for (int f = 0; f < F_; ++f) {
            const float4 wv = wp2[(size_t)f * (D_ / 4)];
            const float hv = h_lds[f];
            y[0] += hv * wv.x; y[1] += hv * wv.y;
            y[2] += hv * wv.z; y[3] += hv * wv.w;
        }
#pragma unroll
        for (int j = 0; j < 4; ++j) acc_out[j] += w * y[j];
        __syncthreads();
    }

    float4 o; o.x = acc_out[0]; o.y = acc_out[1]; o.z = acc_out[2]; o.w = acc_out[3];
    *(float4*)(out + (size_t)n * D_ + d0) = o;
}

extern "C" void kernel_launch(void* const* d_in, const int* in_sizes, int n_in,
                              void* d_out, int out_size, void* d_ws, size_t ws_size,
                              hipStream_t stream) {
    const float* x  = (const float*)d_in[0];
    const float* Wr = (const float*)d_in[1];
    const float* W1 = (const float*)d_in[2];
    const float* b1 = (const float*)d_in[3];
    const float* W2 = (const float*)d_in[4];
    const float* b2 = (const float*)d_in[5];
    float* out = (float*)d_out;

    char* ws = (char*)d_ws;
    int*    cnt   = (int*)(ws + OFF_CNT);
    int*    basep = (int*)(ws + OFF_BASE);
    int*    tidx  = (int*)(ws + OFF_TIDX);
    float*  tw    = (float*)(ws + OFF_TW);
    int*    list  = (int*)(ws + OFF_LIST);
    float*  wgt   = (float*)(ws + OFF_WGT);

    if (ws_size >= WS_MFMA) {
        const int kslabs = (ws_size >= WS_MFMA2) ? 2 : 1;
        int*    slot = (int*)(ws + OFF_SLOT);
        bf16_t* Xb   = (bf16_t*)(ws + OFF_XB);
        bf16_t* W1T  = (bf16_t*)(ws + OFF_W1T);
        bf16_t* W2T  = (bf16_t*)(ws + OFF_W2T);
        bf16_t* H    = (bf16_t*)(ws + OFF_HN);
        float*  Y    = (float*)(ws + OFF_Y);

        hipMemsetAsync(cnt, 0, E_ * sizeof(int), stream);
        router_kernel<<<NTOK, 64, 0, stream>>>(x, Wr, tidx, tw, cnt, list, wgt, slot, 3);
        prefix_kernel<<<1, 64, 0, stream>>>(cnt, basep);
        convert_x_kernel<<<NTOK * D_ / 4 / 256, 256, 0, stream>>>(x, Xb);
        transpose_kernel<<<dim3(F_ / 64, D_ / 64, E_), 256, 0, stream>>>(W1, W1T, D_, F_);
        transpose_kernel<<<dim3(D_ / 64, F_ / 64, E_), 256, 0, stream>>>(W2, W2T, F_, D_);
        mgemm1_kernel<<<dim3(F_ / 128, NTOK / 128, E_), 256, 0, stream>>>(
            Xb, W1T, b1, cnt, basep, list, H);
        mgemm2_kernel<<<dim3(D_ / 128, NTOK / 128, E_ * kslabs), 256, 0, stream>>>(
            H, W2T, b2, cnt, basep, Y);
        combine_kernel<<<NTOK, 256, 0, stream>>>(Y, slot, tw, basep, out, kslabs);
    } else if (ws_size >= WS_OLD) {
        bf16_t* H = (bf16_t*)(ws + OFF_H_OLD);
        hipMemsetAsync(cnt, 0, E_ * sizeof(int), stream);
        router_kernel<<<NTOK, 64, 0, stream>>>(x, Wr, tidx, tw, cnt, list, wgt, nullptr, 1);
        prefix_kernel<<<1, 64, 0, stream>>>(cnt, basep);
        hipMemsetAsync(out, 0, (size_t)NTOK * D_ * sizeof(float), stream);
        gemm1_kernel<<<dim3(F_ / BN, NTOK / BM, E_), 256, 0, stream>>>(
            x, W1, b1, cnt, basep, list, H);
        gemm2_kernel<<<dim3(D_ / BN, NTOK / BM, E_), 256, 0, stream>>>(
            H, W2, b2, cnt, basep, list, wgt, out);
    } else {
        router_kernel<<<NTOK, 64, 0, stream>>>(x, Wr, tidx, tw, cnt, list, wgt, nullptr, 0);
        fallback_expert_kernel<<<NTOK, 256, 0, stream>>>(
            x, W1, b1, W2, b2, tidx, tw, out);
    }
}